// Round 15
// baseline (358.124 us; speedup 1.0000x reference)
//
#include <hip/hip_runtime.h>
#include <cstdint>

// ---------------------------------------------------------------------------
// OFT forward:
//   scale_r = min(1, eps/||R_r||_F)
//   S_r = 0.5*scale_r*(R_r - R_r^T)
//   Q_r = I - 2S + 2S^2  (order-2 Cayley truncation)
//       = I - 2S - 2*(S (*) S)     [ (*) = A.B^T primitive ]
//   filt[o][r*1024+i] = sum_k W[o][r*1024+k] * Q_r[i][k]
//   out[s][o] = sum_f x[s][f] * filt[o][f]
// Primitive: C[m][n] = sum_k A[m][k]*B[n][k]  (A,B row-major bf16)
// Big GEMMs: 256^2 4-phase pipelined kernel (m201-fidelity port):
//   - per-phase {stages-first (long-latency VMEM issue ahead of ds_reads);
//     reads; [lgkmcnt hint]; s_barrier; lgkmcnt(0)+sched_barrier(0);
//     setprio(1); 16 MFMA; setprio(0); s_barrier}
//   - staging spread {P1:A1(s+1), P3:B0+B1(s+2), P4:A0(s+2)}
//     (ledger: newest (s+1)-load is A1@P1; 6 newer at the gate -> vmcnt(6))
//   - 2x-unrolled K-loop (compile-time double-buffer index)
//   - counted vmcnt(6) once per K-tile; bare sync (no memory clobbers)
//   - XOR-swizzled LDS (0 bank conflicts), 2D XCD-chunked block mapping
// ---------------------------------------------------------------------------

typedef __attribute__((ext_vector_type(4))) float facc4;
typedef __attribute__((ext_vector_type(8))) short bfrag8;

__device__ __forceinline__ unsigned short f2bf(float x) {
  union { float f; unsigned int u; } v; v.f = x;
  unsigned int r = v.u + 0x7fffu + ((v.u >> 16) & 1u);
  return (unsigned short)(r >> 16);
}

__device__ __forceinline__ float bf2f(unsigned short b) {
  union { unsigned int u; float f; } v; v.u = ((unsigned int)b) << 16;
  return v.f;
}

__device__ __forceinline__ void gload16(const void* g, void* lds) {
  __builtin_amdgcn_global_load_lds(
      (__attribute__((address_space(1))) void*)(uintptr_t)g,
      (__attribute__((address_space(3))) void*)(uintptr_t)(uint32_t)(uintptr_t)lds,
      16, 0, 0);
}

__device__ __forceinline__ void bar() {
  __builtin_amdgcn_s_barrier();
}

// ---------------- small prep kernels ----------------

__global__ void norm_partials(const float* __restrict__ R, float* __restrict__ part) {
  int r = blockIdx.y, seg = blockIdx.x;           // 4 x 64
  const float* base = R + (long)r * 1048576 + (long)seg * 16384;
  float s = 0.f;
  for (int i = threadIdx.x; i < 4096; i += 256) {
    float4 v = ((const float4*)base)[i];
    s += v.x * v.x + v.y * v.y + v.z * v.z + v.w * v.w;
  }
  __shared__ float red[256];
  red[threadIdx.x] = s;
  __syncthreads();
  for (int off = 128; off; off >>= 1) {
    if (threadIdx.x < off) red[threadIdx.x] += red[threadIdx.x + off];
    __syncthreads();
  }
  if (threadIdx.x == 0) part[r * 64 + seg] = red[0];
}

__global__ void finalize_scale(const float* __restrict__ part, float* __restrict__ scale) {
  int r = blockIdx.x;
  float s = part[r * 64 + threadIdx.x];
  for (int off = 32; off; off >>= 1) s += __shfl_down(s, off);
  if (threadIdx.x == 0) {
    float norm = sqrtf(s);
    const float eps = 5.24288f;                    // 1e-5*1024*1024/sqrt(4)
    scale[r] = (norm <= eps) ? 1.f : eps / norm;
  }
}

// S = 0.5*scale*(R - R^T) -> bf16
__global__ void build_S(const float* __restrict__ R, const float* __restrict__ scale,
                        unsigned short* __restrict__ S) {
  int r = blockIdx.z;
  float c = 0.5f * scale[r];
  const float* Rb = R + (long)r * 1048576;
  unsigned short* Sb = S + (long)r * 1048576;
  int bi = blockIdx.x, bj = blockIdx.y;
  int tx = threadIdx.x, ty = threadIdx.y;          // (32, 8)
  __shared__ float tbuf[32][33];
  for (int yy = ty; yy < 32; yy += 8)
    tbuf[yy][tx] = Rb[(long)(bj * 32 + yy) * 1024 + bi * 32 + tx];
  __syncthreads();
  for (int yy = ty; yy < 32; yy += 8) {
    int i = bi * 32 + yy, j = bj * 32 + tx;
    float s = c * (Rb[(long)i * 1024 + j] - tbuf[tx][yy]);   // tbuf[tx][yy] = R[j][i]
    Sb[(long)i * 1024 + j] = f2bf(s);
  }
}

// ---------------- 128^2 GEMM body (m97 structure): Q = I - 2*E - 2*(A (*) B)
__device__ void gemm_q_body(int bx, int by, int bz,
                            const unsigned short* __restrict__ A,
                            const unsigned short* __restrict__ B,
                            const unsigned short* __restrict__ E,
                            unsigned short* __restrict__ C) {
  __shared__ __align__(16) unsigned short As[4096];   // [128][32]
  __shared__ __align__(16) unsigned short Bs[4096];
  const long LD = 1024, STR = 1048576;
  const int t = threadIdx.x;
  const int l = t & 63;
  const int w = t >> 6;
  const long m0 = (long)bx * 128;
  const long n0 = (long)by * 128;
  A += (long)bz * STR;
  B += (long)bz * STR;
  E += (long)bz * STR;
  C += (long)bz * STR;

  const int srow = t >> 2;
  const int scol = (t & 3) * 8;
  const unsigned short* gA0 = A + (m0 + srow) * LD + scol;
  const unsigned short* gA1 = A + (m0 + srow + 64) * LD + scol;
  const unsigned short* gB0 = B + (n0 + srow) * LD + scol;
  const unsigned short* gB1 = B + (n0 + srow + 64) * LD + scol;

  facc4 acc[4][4];
#pragma unroll
  for (int i = 0; i < 4; ++i)
#pragma unroll
    for (int j = 0; j < 4; ++j) acc[i][j] = (facc4){0.f, 0.f, 0.f, 0.f};

  const int wr = (w >> 1) * 64;
  const int wc = (w & 1) * 64;
  const int fr = l & 15;
  const int kg = (l >> 4) * 8;

  for (int k0 = 0; k0 < 1024; k0 += 32) {
    __syncthreads();
    gload16(gA0 + k0, &As[t * 8]);
    gload16(gA1 + k0, &As[t * 8 + 2048]);
    gload16(gB0 + k0, &Bs[t * 8]);
    gload16(gB1 + k0, &Bs[t * 8 + 2048]);
    __syncthreads();
    bfrag8 af[4], bfr[4];
#pragma unroll
    for (int mf = 0; mf < 4; ++mf)
      af[mf] = *(const bfrag8*)&As[(wr + mf * 16 + fr) * 32 + kg];
#pragma unroll
    for (int nf = 0; nf < 4; ++nf)
      bfr[nf] = *(const bfrag8*)&Bs[(wc + nf * 16 + fr) * 32 + kg];
#pragma unroll
    for (int mf = 0; mf < 4; ++mf)
#pragma unroll
      for (int nf = 0; nf < 4; ++nf)
        acc[mf][nf] = __builtin_amdgcn_mfma_f32_16x16x32_bf16(
            af[mf], bfr[nf], acc[mf][nf], 0, 0, 0);
  }

  const int orow = (l >> 4) * 4;
#pragma unroll
  for (int mf = 0; mf < 4; ++mf) {
#pragma unroll
    for (int nf = 0; nf < 4; ++nf) {
#pragma unroll
      for (int r = 0; r < 4; ++r) {
        long grow = m0 + wr + mf * 16 + orow + r;
        long gcol = n0 + wc + nf * 16 + fr;
        float d = (grow == gcol) ? 1.f : 0.f;
        float sv = bf2f(E[grow * LD + gcol]);
        float v = d - 2.f * sv - 2.f * acc[mf][nf][r];
        C[grow * LD + gcol] = f2bf(v);
      }
    }
  }
}

// ---------------- fused prep: Q-GEMM (blocks 0..255) || converts ------------
// blocks [256, 1024): x f32->bf16 (8388608 float4)
// blocks [1024, 1408): W f32->bf16 (4194304 float4)
__global__ __launch_bounds__(256) void fused_prep(
    const unsigned short* __restrict__ S, unsigned short* __restrict__ Q,
    const float* __restrict__ x, unsigned short* __restrict__ Xb,
    const float* __restrict__ W, unsigned short* __restrict__ Wb) {
  const int b = blockIdx.x;
  if (b < 256) {
    gemm_q_body(b & 7, (b >> 3) & 7, b >> 6, S, S, S, Q);
  } else if (b < 1024) {
    const long stride = 768L * 256;
    for (long i = (long)(b - 256) * 256 + threadIdx.x; i < 8388608; i += stride) {
      float4 v = ((const float4*)x)[i];
      ushort4 o;
      o.x = f2bf(v.x); o.y = f2bf(v.y); o.z = f2bf(v.z); o.w = f2bf(v.w);
      ((ushort4*)Xb)[i] = o;
    }
  } else {
    const long stride = 384L * 256;
    for (long i = (long)(b - 1024) * 256 + threadIdx.x; i < 4194304; i += stride) {
      float4 v = ((const float4*)W)[i];
      ushort4 o;
      o.x = f2bf(v.x); o.y = f2bf(v.y); o.z = f2bf(v.z); o.w = f2bf(v.w);
      ((ushort4*)Wb)[i] = o;
    }
  }
}

// ---------------- 256^2 4-phase GEMM (m201-fidelity): C = A (*) B -----------
#define AC_(db, h) (((db) * 2 + (h)) * 8192)
#define BC_(db, h) (32768 + ((db) * 2 + (h)) * 8192)

template <int F32OUT>
__global__ __launch_bounds__(512, 2) void gemm256(
    const unsigned short* __restrict__ A, long lda, long sA,
    const unsigned short* __restrict__ B, long ldb, long sB,
    void* __restrict__ C, long ldc, long sC, int K,
    int cm, int cn, int ncm) {
  __shared__ __align__(16) unsigned short Lsh[65536];   // 128 KiB
  const int t = threadIdx.x;
  const int l = t & 63;
  const int wid = t >> 6;
  const int wr = wid >> 2;       // 0..1  (wave row)
  const int wc = wid & 3;        // 0..3  (wave col)
  const int fr = l & 15;
  const int lk = l >> 4;
  const int z = blockIdx.z;
  const unsigned short* Ab = A + (long)z * sA;
  const unsigned short* Bb = B + (long)z * sB;

  // 2D XCD-chunked mapping
  const int wg = blockIdx.x;
  const int xcd = wg & 7;
  const int j = wg >> 3;
  const long m0 = (long)((xcd % ncm) * cm + (j % cm)) * 256;
  const long n0 = (long)((xcd / ncm) * cn + (j / cm)) * 256;

  // staging: thread t writes granules t and 512+t of a half-tile (linear LDS),
  // reading the inverse-swizzled global column granule.
  const int r0 = t >> 3, r1 = 64 + (t >> 3);
  const int kg0 = (t & 7) ^ (r0 & 7);
  const int kg1 = (t & 7) ^ (r1 & 7);
  const long soA0 = (long)r0 * lda + kg0 * 8;
  const long soA1 = (long)r1 * lda + kg1 * 8;
  const long soB0 = (long)r0 * ldb + kg0 * 8;
  const long soB1 = (long)r1 * ldb + kg1 * 8;
  const int ldo0 = t * 8, ldo1 = (512 + t) * 8;

  const unsigned short* gA0_ = Ab + m0 * lda;
  const unsigned short* gA1_ = Ab + (m0 + 128) * lda;
  const unsigned short* gB0_ = Bb + n0 * ldb;
  const unsigned short* gB1_ = Bb + (n0 + 128) * ldb;

#define STG_A(h, kt, cb) do { \
    const unsigned short* _g = (h) ? gA1_ : gA0_; \
    gload16(_g + soA0 + (long)(kt) * 64, &Lsh[(cb) + ldo0]); \
    gload16(_g + soA1 + (long)(kt) * 64, &Lsh[(cb) + ldo1]); } while (0)
#define STG_B(h, kt, cb) do { \
    const unsigned short* _g = (h) ? gB1_ : gB0_; \
    gload16(_g + soB0 + (long)(kt) * 64, &Lsh[(cb) + ldo0]); \
    gload16(_g + soB1 + (long)(kt) * 64, &Lsh[(cb) + ldo1]); } while (0)

  const int xk0 = (lk ^ (fr & 7)) * 8;          // kk=0 granule offset (ushorts)
  const int xk1 = ((4 + lk) ^ (fr & 7)) * 8;    // kk=1
  const int rB = (wc & 1) * 64;

  facc4 acc[8][4];
#pragma unroll
  for (int i = 0; i < 8; ++i)
#pragma unroll
    for (int j2 = 0; j2 < 4; ++j2) acc[i][j2] = (facc4){0.f, 0.f, 0.f, 0.f};
  bfrag8 aL[4][2], aH[4][2], bl[2][2], bh[2][2];

#define MMQ(MO, NO, AF, BF) do { \
    __builtin_amdgcn_s_setprio(1); \
    _Pragma("unroll") for (int kk = 0; kk < 2; ++kk) \
    _Pragma("unroll") for (int m = 0; m < 4; ++m) \
    _Pragma("unroll") for (int n = 0; n < 2; ++n) \
      acc[(MO) + m][(NO) + n] = __builtin_amdgcn_mfma_f32_16x16x32_bf16( \
          AF[m][kk], BF[n][kk], acc[(MO) + m][(NO) + n], 0, 0, 0); \
    __builtin_amdgcn_s_setprio(0); } while (0)

#define LGKM0 do { asm volatile("s_waitcnt lgkmcnt(0)"); \
                   __builtin_amdgcn_sched_barrier(0); } while (0)

  // One K-tile, compile-time DB.  Phase skeleton per m201 template:
  // {stages-first; reads; [lgkm hint]; s_barrier; lgkmcnt(0)+SB(0); MFMA;
  //  s_barrier}.  Staging spread: P1:A1(s+1), P3:B0+B1(s+2), P4:A0(s+2).
  // Ledger: newest (s+1)-load = A1@P1; newer-than-it at the P4 gate =
  // B0,B1,A0(s+2) = 6 loads -> vmcnt(6) guarantees tile s+1 landed.
  // B-buffer overwrite legality: last BC_(db,*) reads are P2's bh (each
  // wave's reads complete before it crosses P2's post-MFMA barrier); P3
  // opens after that barrier.  P3's stage writes touch only the B region,
  // its reads only the A region -> stage-first reorder is race-free.
#define TILE(DB, S_) do { \
    const int cAo = (DB) * 16384 + wr * 8192; \
    const int cBo = 32768 + (DB) * 16384 + (wc >> 1) * 8192; \
    /* ---- P1: stage A1(S_+1) first; reads aL(8) + bl(4) ---- */ \
    if ((S_) + 1 < NT) STG_A(1, (S_) + 1, AC_((DB) ^ 1, 1)); \
    _Pragma("unroll") for (int m = 0; m < 4; ++m) { \
      int rb = cAo + (m * 16 + fr) * 64; \
      aL[m][0] = *(const bfrag8*)&Lsh[rb + xk0]; \
      aL[m][1] = *(const bfrag8*)&Lsh[rb + xk1]; \
    } \
    _Pragma("unroll") for (int n = 0; n < 2; ++n) { \
      int rb = cBo + (rB + n * 16 + fr) * 64; \
      bl[n][0] = *(const bfrag8*)&Lsh[rb + xk0]; \
      bl[n][1] = *(const bfrag8*)&Lsh[rb + xk1]; \
    } \
    asm volatile("s_waitcnt lgkmcnt(8)"); \
    bar(); LGKM0; \
    MMQ(0, 0, aL, bl); \
    bar(); \
    /* ---- P2: reads bh(4) ---- */ \
    _Pragma("unroll") for (int n = 0; n < 2; ++n) { \
      int rb = cBo + (rB + 32 + n * 16 + fr) * 64; \
      bh[n][0] = *(const bfrag8*)&Lsh[rb + xk0]; \
      bh[n][1] = *(const bfrag8*)&Lsh[rb + xk1]; \
    } \
    bar(); LGKM0; \
    MMQ(0, 2, aL, bh); \
    bar(); \
    /* ---- P3: stage B0+B1(S_+2) first; reads aH(8) ---- */ \
    if ((S_) + 2 < NT) { STG_B(0, (S_) + 2, BC_((DB), 0)); \
                         STG_B(1, (S_) + 2, BC_((DB), 1)); } \
    _Pragma("unroll") for (int m = 0; m < 4; ++m) { \
      int rb = cAo + (64 + m * 16 + fr) * 64; \
      aH[m][0] = *(const bfrag8*)&Lsh[rb + xk0]; \
      aH[m][1] = *(const bfrag8*)&Lsh[rb + xk1]; \
    } \
    asm volatile("s_waitcnt lgkmcnt(4)"); \
    bar(); LGKM0; \
    MMQ(4, 0, aH, bl); \
    bar(); \
    /* ---- P4: stage A0(S_+2); vmcnt gate ---- */ \
    if ((S_) + 2 < NT) STG_A(0, (S_) + 2, AC_((DB), 0)); \
    bar(); \
    MMQ(4, 2, aH, bh); \
    if ((S_) + 2 < NT) asm volatile("s_waitcnt vmcnt(6)"); \
    else               asm volatile("s_waitcnt vmcnt(0)"); \
    __builtin_amdgcn_sched_barrier(0); \
    bar(); \
  } while (0)

  // prologue: tile0 fully + 3 half-tiles of tile1; leave 6 loads in flight
  STG_B(0, 0, BC_(0, 0));
  STG_A(0, 0, AC_(0, 0));
  STG_B(1, 0, BC_(0, 1));
  STG_A(1, 0, AC_(0, 1));
  STG_B(0, 1, BC_(1, 0));
  STG_A(0, 1, AC_(1, 0));
  STG_B(1, 1, BC_(1, 1));
  asm volatile("s_waitcnt vmcnt(6)");
  __builtin_amdgcn_sched_barrier(0);
  bar();

  const int NT = K >> 6;   // even for all our launches (K multiple of 128)
  for (int s = 0; s < NT; s += 2) {
    TILE(0, s);
    TILE(1, s + 1);
  }

  // epilogue
#pragma unroll
  for (int m = 0; m < 8; ++m) {
#pragma unroll
    for (int n = 0; n < 4; ++n) {
#pragma unroll
      for (int r = 0; r < 4; ++r) {
        long grow = m0 + wr * 128 + m * 16 + lk * 4 + r;
        long gcol = n0 + wc * 64 + n * 16 + fr;
        if (F32OUT) {
          ((float*)C + (long)z * sC)[grow * ldc + gcol] = acc[m][n][r];
        } else {
          ((unsigned short*)C + (long)z * sC)[grow * ldc + gcol] = f2bf(acc[m][n][r]);
        }
      }
    }
  }
#undef STG_A
#undef STG_B
#undef MMQ
#undef LGKM0
#undef TILE
}

// ---------------- workspace layout (bytes) ----------------
static const size_t OFF_SCALE = 0;
static const size_t OFF_PART  = 1024;
static const size_t OFF_S     = 4ull << 20;
static const size_t OFF_PA    = 12ull << 20;   // Q bf16 [4][1024][1024]
static const size_t OFF_W     = 28ull << 20;   // W bf16 [4096][4096]
static const size_t OFF_FILT  = 60ull << 20;   // filt bf16 (row=o, col=f)
static const size_t OFF_XBF   = 92ull << 20;   // x bf16 [8192][4096]

extern "C" void kernel_launch(void* const* d_in, const int* in_sizes, int n_in,
                              void* d_out, int out_size, void* d_ws, size_t ws_size,
                              hipStream_t stream) {
  const float* x    = (const float*)d_in[0];
  const float* oftR = (const float*)d_in[1];
  const float* W    = (const float*)d_in[2];
  char* ws = (char*)d_ws;
  float* scale = (float*)(ws + OFF_SCALE);
  float* part  = (float*)(ws + OFF_PART);
  unsigned short* S  = (unsigned short*)(ws + OFF_S);
  unsigned short* Q  = (unsigned short*)(ws + OFF_PA);
  unsigned short* Wb = (unsigned short*)(ws + OFF_W);
  unsigned short* Fl = (unsigned short*)(ws + OFF_FILT);
  unsigned short* Xb = (unsigned short*)(ws + OFF_XBF);

  norm_partials<<<dim3(64, 4), 256, 0, stream>>>(oftR, part);
  finalize_scale<<<4, 64, 0, stream>>>(part, scale);
  build_S<<<dim3(32, 32, 4), dim3(32, 8), 0, stream>>>(oftR, scale, S);

  // Q = I - 2S - 2*(S (*) S)   [GEMM blocks]  ||  x,W bf16 converts
  fused_prep<<<1408, 256, 0, stream>>>(S, Q, x, Xb, W, Wb);

  // filt(:, blk r) = W_bf(:, blk r) (*) Q_r  (16 m-tiles x 4 n-tiles, batch 4)
  gemm256<0><<<dim3(64, 1, 4), 512, 0, stream>>>(
      Wb, 4096, 1024, Q, 1024, 1048576, Fl, 4096, 1024, 1024, 4, 2, 4);
  // out = x_bf (*) filt   (32 m-tiles x 16 n-tiles)
  gemm256<1><<<dim3(512, 1, 1), 512, 0, stream>>>(
      Xb, 4096, 0, Fl, 4096, 0, d_out, 4096, 0, 4096, 8, 8, 4);
}

// Round 16
// 352.894 us; speedup vs baseline: 1.0148x; 1.0148x over previous
//
#include <hip/hip_runtime.h>
#include <cstdint>

// ---------------------------------------------------------------------------
// OFT forward:
//   scale_r = min(1, eps/||R_r||_F)
//   S_r = 0.5*scale_r*(R_r - R_r^T)
//   Q_r = I - 2S + 2S^2  (order-2 Cayley truncation)
//       = I - 2S - 2*(S (*) S)     [ (*) = A.B^T primitive ]
//   filt[o][r*1024+i] = sum_k W[o][r*1024+k] * Q_r[i][k]
//   out[s][o] = sum_f x[s][f] * filt[o][f]
// Primitive: C[m][n] = sum_k A[m][k]*B[n][k]  (A,B row-major bf16)
// Big GEMMs: 256^2 4-phase pipelined kernel (m201-fidelity port):
//   - per-phase {reads; stage; [lgkmcnt(8) if 12 reads]; s_barrier;
//     lgkmcnt(0)+sched_barrier(0); setprio(1); 16 MFMA; setprio(0); s_barrier}
//   - staging spread {P1:A1(s+1), P3:B0+B1(s+2), P4:A0(s+2)}
//     (ledger: newest (s+1)-load is A1@P1; 6 newer at the gate -> vmcnt(6))
//   - 2x-unrolled K-loop (compile-time double-buffer index)
//   - counted vmcnt(6) once per K-tile; bare sync (no memory clobbers)
//   - XOR-swizzled LDS (0 bank conflicts), 2D XCD-chunked block mapping
// FINAL: best-measured configuration (round 14, 353.25 us).
//   Round-15 A/B showed stages-before-reads and an extra P3 lgkmcnt hint
//   both REGRESS (-5 us): critical path is the LDS port + post-barrier
//   drain, not VMEM issue latency. Reads-first ordering is the optimum.
// ---------------------------------------------------------------------------

typedef __attribute__((ext_vector_type(4))) float facc4;
typedef __attribute__((ext_vector_type(8))) short bfrag8;

__device__ __forceinline__ unsigned short f2bf(float x) {
  union { float f; unsigned int u; } v; v.f = x;
  unsigned int r = v.u + 0x7fffu + ((v.u >> 16) & 1u);
  return (unsigned short)(r >> 16);
}

__device__ __forceinline__ float bf2f(unsigned short b) {
  union { unsigned int u; float f; } v; v.u = ((unsigned int)b) << 16;
  return v.f;
}

__device__ __forceinline__ void gload16(const void* g, void* lds) {
  __builtin_amdgcn_global_load_lds(
      (__attribute__((address_space(1))) void*)(uintptr_t)g,
      (__attribute__((address_space(3))) void*)(uintptr_t)(uint32_t)(uintptr_t)lds,
      16, 0, 0);
}

__device__ __forceinline__ void bar() {
  __builtin_amdgcn_s_barrier();
}

// ---------------- small prep kernels ----------------

__global__ void norm_partials(const float* __restrict__ R, float* __restrict__ part) {
  int r = blockIdx.y, seg = blockIdx.x;           // 4 x 64
  const float* base = R + (long)r * 1048576 + (long)seg * 16384;
  float s = 0.f;
  for (int i = threadIdx.x; i < 4096; i += 256) {
    float4 v = ((const float4*)base)[i];
    s += v.x * v.x + v.y * v.y + v.z * v.z + v.w * v.w;
  }
  __shared__ float red[256];
  red[threadIdx.x] = s;
  __syncthreads();
  for (int off = 128; off; off >>= 1) {
    if (threadIdx.x < off) red[threadIdx.x] += red[threadIdx.x + off];
    __syncthreads();
  }
  if (threadIdx.x == 0) part[r * 64 + seg] = red[0];
}

__global__ void finalize_scale(const float* __restrict__ part, float* __restrict__ scale) {
  int r = blockIdx.x;
  float s = part[r * 64 + threadIdx.x];
  for (int off = 32; off; off >>= 1) s += __shfl_down(s, off);
  if (threadIdx.x == 0) {
    float norm = sqrtf(s);
    const float eps = 5.24288f;                    // 1e-5*1024*1024/sqrt(4)
    scale[r] = (norm <= eps) ? 1.f : eps / norm;
  }
}

// S = 0.5*scale*(R - R^T) -> bf16
__global__ void build_S(const float* __restrict__ R, const float* __restrict__ scale,
                        unsigned short* __restrict__ S) {
  int r = blockIdx.z;
  float c = 0.5f * scale[r];
  const float* Rb = R + (long)r * 1048576;
  unsigned short* Sb = S + (long)r * 1048576;
  int bi = blockIdx.x, bj = blockIdx.y;
  int tx = threadIdx.x, ty = threadIdx.y;          // (32, 8)
  __shared__ float tbuf[32][33];
  for (int yy = ty; yy < 32; yy += 8)
    tbuf[yy][tx] = Rb[(long)(bj * 32 + yy) * 1024 + bi * 32 + tx];
  __syncthreads();
  for (int yy = ty; yy < 32; yy += 8) {
    int i = bi * 32 + yy, j = bj * 32 + tx;
    float s = c * (Rb[(long)i * 1024 + j] - tbuf[tx][yy]);   // tbuf[tx][yy] = R[j][i]
    Sb[(long)i * 1024 + j] = f2bf(s);
  }
}

// ---------------- 128^2 GEMM body (m97 structure): Q = I - 2*E - 2*(A (*) B)
__device__ void gemm_q_body(int bx, int by, int bz,
                            const unsigned short* __restrict__ A,
                            const unsigned short* __restrict__ B,
                            const unsigned short* __restrict__ E,
                            unsigned short* __restrict__ C) {
  __shared__ __align__(16) unsigned short As[4096];   // [128][32]
  __shared__ __align__(16) unsigned short Bs[4096];
  const long LD = 1024, STR = 1048576;
  const int t = threadIdx.x;
  const int l = t & 63;
  const int w = t >> 6;
  const long m0 = (long)bx * 128;
  const long n0 = (long)by * 128;
  A += (long)bz * STR;
  B += (long)bz * STR;
  E += (long)bz * STR;
  C += (long)bz * STR;

  const int srow = t >> 2;
  const int scol = (t & 3) * 8;
  const unsigned short* gA0 = A + (m0 + srow) * LD + scol;
  const unsigned short* gA1 = A + (m0 + srow + 64) * LD + scol;
  const unsigned short* gB0 = B + (n0 + srow) * LD + scol;
  const unsigned short* gB1 = B + (n0 + srow + 64) * LD + scol;

  facc4 acc[4][4];
#pragma unroll
  for (int i = 0; i < 4; ++i)
#pragma unroll
    for (int j = 0; j < 4; ++j) acc[i][j] = (facc4){0.f, 0.f, 0.f, 0.f};

  const int wr = (w >> 1) * 64;
  const int wc = (w & 1) * 64;
  const int fr = l & 15;
  const int kg = (l >> 4) * 8;

  for (int k0 = 0; k0 < 1024; k0 += 32) {
    __syncthreads();
    gload16(gA0 + k0, &As[t * 8]);
    gload16(gA1 + k0, &As[t * 8 + 2048]);
    gload16(gB0 + k0, &Bs[t * 8]);
    gload16(gB1 + k0, &Bs[t * 8 + 2048]);
    __syncthreads();
    bfrag8 af[4], bfr[4];
#pragma unroll
    for (int mf = 0; mf < 4; ++mf)
      af[mf] = *(const bfrag8*)&As[(wr + mf * 16 + fr) * 32 + kg];
#pragma unroll
    for (int nf = 0; nf < 4; ++nf)
      bfr[nf] = *(const bfrag8*)&Bs[(wc + nf * 16 + fr) * 32 + kg];
#pragma unroll
    for (int mf = 0; mf < 4; ++mf)
#pragma unroll
      for (int nf = 0; nf < 4; ++nf)
        acc[mf][nf] = __builtin_amdgcn_mfma_f32_16x16x32_bf16(
            af[mf], bfr[nf], acc[mf][nf], 0, 0, 0);
  }

  const int orow = (l >> 4) * 4;
#pragma unroll
  for (int mf = 0; mf < 4; ++mf) {
#pragma unroll
    for (int nf = 0; nf < 4; ++nf) {
#pragma unroll
      for (int r = 0; r < 4; ++r) {
        long grow = m0 + wr + mf * 16 + orow + r;
        long gcol = n0 + wc + nf * 16 + fr;
        float d = (grow == gcol) ? 1.f : 0.f;
        float sv = bf2f(E[grow * LD + gcol]);
        float v = d - 2.f * sv - 2.f * acc[mf][nf][r];
        C[grow * LD + gcol] = f2bf(v);
      }
    }
  }
}

// ---------------- fused prep: Q-GEMM (blocks 0..255) || converts ------------
// blocks [256, 1024): x f32->bf16 (8388608 float4)
// blocks [1024, 1408): W f32->bf16 (4194304 float4)
__global__ __launch_bounds__(256) void fused_prep(
    const unsigned short* __restrict__ S, unsigned short* __restrict__ Q,
    const float* __restrict__ x, unsigned short* __restrict__ Xb,
    const float* __restrict__ W, unsigned short* __restrict__ Wb) {
  const int b = blockIdx.x;
  if (b < 256) {
    gemm_q_body(b & 7, (b >> 3) & 7, b >> 6, S, S, S, Q);
  } else if (b < 1024) {
    const long stride = 768L * 256;
    for (long i = (long)(b - 256) * 256 + threadIdx.x; i < 8388608; i += stride) {
      float4 v = ((const float4*)x)[i];
      ushort4 o;
      o.x = f2bf(v.x); o.y = f2bf(v.y); o.z = f2bf(v.z); o.w = f2bf(v.w);
      ((ushort4*)Xb)[i] = o;
    }
  } else {
    const long stride = 384L * 256;
    for (long i = (long)(b - 1024) * 256 + threadIdx.x; i < 4194304; i += stride) {
      float4 v = ((const float4*)W)[i];
      ushort4 o;
      o.x = f2bf(v.x); o.y = f2bf(v.y); o.z = f2bf(v.z); o.w = f2bf(v.w);
      ((ushort4*)Wb)[i] = o;
    }
  }
}

// ---------------- 256^2 4-phase GEMM (m201-fidelity): C = A (*) B -----------
#define AC_(db, h) (((db) * 2 + (h)) * 8192)
#define BC_(db, h) (32768 + ((db) * 2 + (h)) * 8192)

template <int F32OUT>
__global__ __launch_bounds__(512, 2) void gemm256(
    const unsigned short* __restrict__ A, long lda, long sA,
    const unsigned short* __restrict__ B, long ldb, long sB,
    void* __restrict__ C, long ldc, long sC, int K,
    int cm, int cn, int ncm) {
  __shared__ __align__(16) unsigned short Lsh[65536];   // 128 KiB
  const int t = threadIdx.x;
  const int l = t & 63;
  const int wid = t >> 6;
  const int wr = wid >> 2;       // 0..1  (wave row)
  const int wc = wid & 3;        // 0..3  (wave col)
  const int fr = l & 15;
  const int lk = l >> 4;
  const int z = blockIdx.z;
  const unsigned short* Ab = A + (long)z * sA;
  const unsigned short* Bb = B + (long)z * sB;

  // 2D XCD-chunked mapping
  const int wg = blockIdx.x;
  const int xcd = wg & 7;
  const int j = wg >> 3;
  const long m0 = (long)((xcd % ncm) * cm + (j % cm)) * 256;
  const long n0 = (long)((xcd / ncm) * cn + (j / cm)) * 256;

  // staging: thread t writes granules t and 512+t of a half-tile (linear LDS),
  // reading the inverse-swizzled global column granule.
  const int r0 = t >> 3, r1 = 64 + (t >> 3);
  const int kg0 = (t & 7) ^ (r0 & 7);
  const int kg1 = (t & 7) ^ (r1 & 7);
  const long soA0 = (long)r0 * lda + kg0 * 8;
  const long soA1 = (long)r1 * lda + kg1 * 8;
  const long soB0 = (long)r0 * ldb + kg0 * 8;
  const long soB1 = (long)r1 * ldb + kg1 * 8;
  const int ldo0 = t * 8, ldo1 = (512 + t) * 8;

  const unsigned short* gA0_ = Ab + m0 * lda;
  const unsigned short* gA1_ = Ab + (m0 + 128) * lda;
  const unsigned short* gB0_ = Bb + n0 * ldb;
  const unsigned short* gB1_ = Bb + (n0 + 128) * ldb;

#define STG_A(h, kt, cb) do { \
    const unsigned short* _g = (h) ? gA1_ : gA0_; \
    gload16(_g + soA0 + (long)(kt) * 64, &Lsh[(cb) + ldo0]); \
    gload16(_g + soA1 + (long)(kt) * 64, &Lsh[(cb) + ldo1]); } while (0)
#define STG_B(h, kt, cb) do { \
    const unsigned short* _g = (h) ? gB1_ : gB0_; \
    gload16(_g + soB0 + (long)(kt) * 64, &Lsh[(cb) + ldo0]); \
    gload16(_g + soB1 + (long)(kt) * 64, &Lsh[(cb) + ldo1]); } while (0)

  const int xk0 = (lk ^ (fr & 7)) * 8;          // kk=0 granule offset (ushorts)
  const int xk1 = ((4 + lk) ^ (fr & 7)) * 8;    // kk=1
  const int rB = (wc & 1) * 64;

  facc4 acc[8][4];
#pragma unroll
  for (int i = 0; i < 8; ++i)
#pragma unroll
    for (int j2 = 0; j2 < 4; ++j2) acc[i][j2] = (facc4){0.f, 0.f, 0.f, 0.f};
  bfrag8 aL[4][2], aH[4][2], bl[2][2], bh[2][2];

#define MMQ(MO, NO, AF, BF) do { \
    __builtin_amdgcn_s_setprio(1); \
    _Pragma("unroll") for (int kk = 0; kk < 2; ++kk) \
    _Pragma("unroll") for (int m = 0; m < 4; ++m) \
    _Pragma("unroll") for (int n = 0; n < 2; ++n) \
      acc[(MO) + m][(NO) + n] = __builtin_amdgcn_mfma_f32_16x16x32_bf16( \
          AF[m][kk], BF[n][kk], acc[(MO) + m][(NO) + n], 0, 0, 0); \
    __builtin_amdgcn_s_setprio(0); } while (0)

#define LGKM0 do { asm volatile("s_waitcnt lgkmcnt(0)"); \
                   __builtin_amdgcn_sched_barrier(0); } while (0)

  // One K-tile, compile-time DB.  Phase skeleton per m201 template:
  // {reads; stage; [lgkmcnt(8)]; s_barrier; lgkmcnt(0)+SB(0); MFMA; s_barrier}
  // Staging spread: P1:A1(s+1), P3:B0+B1(s+2), P4:A0(s+2).
  // Ledger: newest (s+1)-load = A1@P1; newer-than-it at the P4 gate =
  // B0,B1,A0(s+2) = 6 loads -> vmcnt(6) guarantees tile s+1 landed.
  // B-buffer overwrite legality: last BC_(db,*) reads are P2's bh (pre-P2
  // barrier); P3 opens after that barrier.
#define TILE(DB, S_) do { \
    const int cAo = (DB) * 16384 + wr * 8192; \
    const int cBo = 32768 + (DB) * 16384 + (wc >> 1) * 8192; \
    /* ---- P1: reads aL(8) + bl(4); stage A1(S_+1) ---- */ \
    _Pragma("unroll") for (int m = 0; m < 4; ++m) { \
      int rb = cAo + (m * 16 + fr) * 64; \
      aL[m][0] = *(const bfrag8*)&Lsh[rb + xk0]; \
      aL[m][1] = *(const bfrag8*)&Lsh[rb + xk1]; \
    } \
    _Pragma("unroll") for (int n = 0; n < 2; ++n) { \
      int rb = cBo + (rB + n * 16 + fr) * 64; \
      bl[n][0] = *(const bfrag8*)&Lsh[rb + xk0]; \
      bl[n][1] = *(const bfrag8*)&Lsh[rb + xk1]; \
    } \
    if ((S_) + 1 < NT) STG_A(1, (S_) + 1, AC_((DB) ^ 1, 1)); \
    asm volatile("s_waitcnt lgkmcnt(8)"); \
    bar(); LGKM0; \
    MMQ(0, 0, aL, bl); \
    bar(); \
    /* ---- P2: reads bh(4) ---- */ \
    _Pragma("unroll") for (int n = 0; n < 2; ++n) { \
      int rb = cBo + (rB + 32 + n * 16 + fr) * 64; \
      bh[n][0] = *(const bfrag8*)&Lsh[rb + xk0]; \
      bh[n][1] = *(const bfrag8*)&Lsh[rb + xk1]; \
    } \
    bar(); LGKM0; \
    MMQ(0, 2, aL, bh); \
    bar(); \
    /* ---- P3: reads aH(8); stage B0(S_+2), B1(S_+2) ---- */ \
    _Pragma("unroll") for (int m = 0; m < 4; ++m) { \
      int rb = cAo + (64 + m * 16 + fr) * 64; \
      aH[m][0] = *(const bfrag8*)&Lsh[rb + xk0]; \
      aH[m][1] = *(const bfrag8*)&Lsh[rb + xk1]; \
    } \
    if ((S_) + 2 < NT) { STG_B(0, (S_) + 2, BC_((DB), 0)); \
                         STG_B(1, (S_) + 2, BC_((DB), 1)); } \
    bar(); LGKM0; \
    MMQ(4, 0, aH, bl); \
    bar(); \
    /* ---- P4: stage A0(S_+2); vmcnt gate ---- */ \
    if ((S_) + 2 < NT) STG_A(0, (S_) + 2, AC_((DB), 0)); \
    bar(); \
    MMQ(4, 2, aH, bh); \
    if ((S_) + 2 < NT) asm volatile("s_waitcnt vmcnt(6)"); \
    else               asm volatile("s_waitcnt vmcnt(0)"); \
    __builtin_amdgcn_sched_barrier(0); \
    bar(); \
  } while (0)

  // prologue: tile0 fully + 3 half-tiles of tile1; leave 6 loads in flight
  STG_B(0, 0, BC_(0, 0));
  STG_A(0, 0, AC_(0, 0));
  STG_B(1, 0, BC_(0, 1));
  STG_A(1, 0, AC_(0, 1));
  STG_B(0, 1, BC_(1, 0));
  STG_A(0, 1, AC_(1, 0));
  STG_B(1, 1, BC_(1, 1));
  asm volatile("s_waitcnt vmcnt(6)");
  __builtin_amdgcn_sched_barrier(0);
  bar();

  const int NT = K >> 6;   // even for all our launches (K multiple of 128)
  for (int s = 0; s < NT; s += 2) {
    TILE(0, s);
    TILE(1, s + 1);
  }

  // epilogue
#pragma unroll
  for (int m = 0; m < 8; ++m) {
#pragma unroll
    for (int n = 0; n < 4; ++n) {
#pragma unroll
      for (int r = 0; r < 4; ++r) {
        long grow = m0 + wr * 128 + m * 16 + lk * 4 + r;
        long gcol = n0 + wc * 64 + n * 16 + fr;
        if (F32OUT) {
          ((float*)C + (long)z * sC)[grow * ldc + gcol] = acc[m][n][r];
        } else {
          ((unsigned short*)C + (long)z * sC)[grow * ldc + gcol] = f2bf(acc[m][n][r]);
        }
      }
    }
  }
#undef STG_A
#undef STG_B
#undef MMQ
#undef LGKM0
#undef TILE
}

// ---------------- workspace layout (bytes) ----------------
static const size_t OFF_SCALE = 0;
static const size_t OFF_PART  = 1024;
static const size_t OFF_S     = 4ull << 20;
static const size_t OFF_PA    = 12ull << 20;   // Q bf16 [4][1024][1024]
static const size_t OFF_W     = 28ull << 20;   // W bf16 [4096][4096]
static const size_t OFF_FILT  = 60ull << 20;   // filt bf16 (row=o, col=f)
static const size_t OFF_XBF   = 92ull << 20;   // x bf16 [8192][4096]

extern "C" void kernel_launch(void* const* d_in, const int* in_sizes, int n_in,
                              void* d_out, int out_size, void* d_ws, size_t ws_size,
                              hipStream_t stream) {
  const float* x    = (const float*)d_in[0];
  const float* oftR = (const float*)d_in[1];
  const float* W    = (const float*)d_in[2];
  char* ws = (char*)d_ws;
  float* scale = (float*)(ws + OFF_SCALE);
  float* part  = (float*)(ws + OFF_PART);
  unsigned short* S  = (unsigned short*)(ws + OFF_S);
  unsigned short* Q  = (unsigned short*)(ws + OFF_PA);
  unsigned short* Wb = (unsigned short*)(ws + OFF_W);
  unsigned short* Fl = (unsigned short*)(ws + OFF_FILT);
  unsigned short* Xb = (unsigned short*)(ws + OFF_XBF);

  norm_partials<<<dim3(64, 4), 256, 0, stream>>>(oftR, part);
  finalize_scale<<<4, 64, 0, stream>>>(part, scale);
  build_S<<<dim3(32, 32, 4), dim3(32, 8), 0, stream>>>(oftR, scale, S);

  // Q = I - 2S - 2*(S (*) S)   [GEMM blocks]  ||  x,W bf16 converts
  fused_prep<<<1408, 256, 0, stream>>>(S, Q, x, Xb, W, Wb);

  // filt(:, blk r) = W_bf(:, blk r) (*) Q_r  (16 m-tiles x 4 n-tiles, batch 4)
  gemm256<0><<<dim3(64, 1, 4), 512, 0, stream>>>(
      Wb, 4096, 1024, Q, 1024, 1048576, Fl, 4096, 1024, 1024, 4, 2, 4);
  // out = x_bf (*) filt   (32 m-tiles x 16 n-tiles)
  gemm256<1><<<dim3(512, 1, 1), 512, 0, stream>>>(
      Xb, 4096, 0, Fl, 4096, 0, d_out, 4096, 0, 4096, 8, 8, 4);
}